// Round 4
// baseline (870.868 us; speedup 1.0000x reference)
//
#include <hip/hip_runtime.h>

constexpr int Wd = 512;
constexpr int PLANE = 512 * 512;

struct Add { static constexpr bool value = true; };
struct Sub { static constexpr bool value = false; };

// ---------------- kernel 1: per-plane-segment min/max partials ----------------
__global__ __launch_bounds__(256) void minmax_part(const float* __restrict__ pred,
                                                   const float* __restrict__ targ,
                                                   float* __restrict__ pmx,
                                                   float* __restrict__ pmn) {
    int bx = blockIdx.x;
    int plane = bx >> 3, seg = bx & 7;
    size_t base = (size_t)plane * PLANE + (size_t)seg * 32768;
    const float4* p4 = reinterpret_cast<const float4*>(pred + base);
    const float4* t4 = reinterpret_cast<const float4*>(targ + base);
    float mx = -3.0e38f, mn = 3.0e38f;
    for (int i = threadIdx.x; i < 8192; i += 256) {
        float4 a = p4[i], b = t4[i];
        mx = fmaxf(mx, fmaxf(fmaxf(fmaxf(a.x, b.x), fmaxf(a.y, b.y)),
                             fmaxf(fmaxf(a.z, b.z), fmaxf(a.w, b.w))));
        mn = fminf(mn, fminf(fminf(fminf(a.x, b.x), fminf(a.y, b.y)),
                             fminf(fminf(a.z, b.z), fminf(a.w, b.w))));
    }
    #pragma unroll
    for (int off = 32; off; off >>= 1) {
        mx = fmaxf(mx, __shfl_down(mx, off));
        mn = fminf(mn, __shfl_down(mn, off));
    }
    __shared__ float smx[4], smn[4];
    int wid = threadIdx.x >> 6, lane = threadIdx.x & 63;
    if (lane == 0) { smx[wid] = mx; smn[wid] = mn; }
    __syncthreads();
    if (threadIdx.x == 0) {
        pmx[bx] = fmaxf(fmaxf(smx[0], smx[1]), fmaxf(smx[2], smx[3]));
        pmn[bx] = fminf(fminf(smn[0], smn[1]), fminf(smn[2], smn[3]));
    }
}

// ---------------- kernel 2: finalize c1/c2 per plane ----------------
__global__ void minmax_fin(const float* __restrict__ pmx, const float* __restrict__ pmn,
                           float* __restrict__ c1s, float* __restrict__ c2s, int planes) {
    int p = blockIdx.x * blockDim.x + threadIdx.x;
    if (p < planes) {
        float mx = -3.0e38f, mn = 3.0e38f;
        for (int s = 0; s < 8; ++s) {
            mx = fmaxf(mx, pmx[p * 8 + s]);
            mn = fminf(mn, pmn[p * 8 + s]);
        }
        float dr = fmaxf(mx - mn, 1e-6f);
        float a = 0.01f * dr, b = 0.03f * dr;
        c1s[p] = a * a;
        c2s[p] = b * b;
    }
}

// ---------------- kernel 3: fused separable SSIM, shuffle-based ----------------
// Grid: planes*8 blocks x 512 threads = 8 independent waves/block. Each wave
// owns 8 output rows; lane c owns columns 8c..8c+7. Vertical 11-row running
// box sums of {p,t,pp,tt,pt} in registers; horizontal 11-col box sum via
// per-lane prefix sums + neighbor-lane __shfl. No LDS tiles, no barriers.
// 768 blocks * 8 waves = 6144 waves -> 24 waves/CU (75% cap) vs 37.5% before.
__global__ __launch_bounds__(512, 6) void ssim_main(const float* __restrict__ pred,
                                                    const float* __restrict__ targ,
                                                    const float* __restrict__ c1s,
                                                    const float* __restrict__ c2s,
                                                    float* __restrict__ parts) {
    __shared__ float red[8];
    int bx = blockIdx.x;
    int plane = bx >> 3, tile = bx & 7;
    int wid = threadIdx.x >> 6, c = threadIdx.x & 63;
    const float c1 = c1s[plane], c2 = c2s[plane];
    const float* Pg = pred + (size_t)plane * PLANE;
    const float* Tg = targ + (size_t)plane * PLANE;
    int r0 = tile * 64 + wid * 8;  // first output row of this wave
    const bool lane0 = (c == 0), lane63 = (c == 63);

    float vsP[8], vsT[8], vsPP[8], vsTT[8], vsPT[8];
    #pragma unroll
    for (int k = 0; k < 8; ++k) { vsP[k] = 0; vsT[k] = 0; vsPP[k] = 0; vsTT[k] = 0; vsPT[k] = 0; }

    // S = Add (row enters window) or Sub (row leaves window)
    auto acc = [&](int r, auto S) {
        if ((unsigned)r < 512u) {
            const float4* prow = reinterpret_cast<const float4*>(Pg + (size_t)r * Wd);
            const float4* trow = reinterpret_cast<const float4*>(Tg + (size_t)r * Wd);
            float4 a0 = prow[2 * c], a1 = prow[2 * c + 1];
            float4 b0 = trow[2 * c], b1 = trow[2 * c + 1];
            float pa[8] = {a0.x, a0.y, a0.z, a0.w, a1.x, a1.y, a1.z, a1.w};
            float tb[8] = {b0.x, b0.y, b0.z, b0.w, b1.x, b1.y, b1.z, b1.w};
            #pragma unroll
            for (int k = 0; k < 8; ++k) {
                if (decltype(S)::value) {
                    vsP[k]  += pa[k];
                    vsT[k]  += tb[k];
                    vsPP[k] = fmaf(pa[k], pa[k], vsPP[k]);
                    vsTT[k] = fmaf(tb[k], tb[k], vsTT[k]);
                    vsPT[k] = fmaf(pa[k], tb[k], vsPT[k]);
                } else {
                    vsP[k]  -= pa[k];
                    vsT[k]  -= tb[k];
                    vsPP[k] = fmaf(-pa[k], pa[k], vsPP[k]);
                    vsTT[k] = fmaf(-tb[k], tb[k], vsTT[k]);
                    vsPT[k] = fmaf(-pa[k], tb[k], vsPT[k]);
                }
            }
        }
    };

    // Horizontal 11-tap box sum over this lane's 8 columns using neighbor shfl.
    auto hsum = [&](const float v[8], float H[8]) {
        float P[8];
        P[0] = v[0];
        #pragma unroll
        for (int k = 1; k < 8; ++k) P[k] = P[k - 1] + v[k];
        float T = P[7];
        float Tm  = __shfl_up(T, 1);
        float Pm2 = __shfl_up(P[2], 1);
        float Pm3 = __shfl_up(P[3], 1);
        float Pm4 = __shfl_up(P[4], 1);
        float Pm5 = __shfl_up(P[5], 1);
        float Pm6 = __shfl_up(P[6], 1);
        if (lane0) { Tm = 0; Pm2 = 0; Pm3 = 0; Pm4 = 0; Pm5 = 0; Pm6 = 0; }
        float Pp0 = __shfl_down(P[0], 1);
        float Pp1 = __shfl_down(P[1], 1);
        float Pp2 = __shfl_down(P[2], 1);
        float Pp3 = __shfl_down(P[3], 1);
        float Pp4 = __shfl_down(P[4], 1);
        if (lane63) { Pp0 = 0; Pp1 = 0; Pp2 = 0; Pp3 = 0; Pp4 = 0; }
        H[0] = (Tm - Pm2) + P[5];
        H[1] = (Tm - Pm3) + P[6];
        H[2] = (Tm - Pm4) + T;
        H[3] = (Tm - Pm5) + (T + Pp0);
        H[4] = (Tm - Pm6) + (T + Pp1);
        H[5] = T + Pp2;
        H[6] = (T - P[0]) + Pp3;
        H[7] = (T - P[1]) + Pp4;
    };

    // init vertical window: rows r0-5 .. r0+4
    for (int r = r0 - 5; r <= r0 + 4; ++r) acc(r, Add{});

    float lsum = 0.0f;
    #pragma unroll 1
    for (int it = 0; it < 8; ++it) {
        int orow = r0 + it;
        acc(orow + 5, Add{});  // window now rows orow-5..orow+5

        float H[5][8];
        hsum(vsP,  H[0]);
        hsum(vsT,  H[1]);
        hsum(vsPP, H[2]);
        hsum(vsTT, H[3]);
        hsum(vsPT, H[4]);

        constexpr float inv = 1.0f / 121.0f;
        #pragma unroll
        for (int i = 0; i < 8; ++i) {
            float mup = H[0][i] * inv, mut = H[1][i] * inv;
            float spp = fmaxf(H[2][i] * inv - mup * mup, 0.0f);
            float stt = fmaxf(H[3][i] * inv - mut * mut, 0.0f);
            float spt = H[4][i] * inv - mup * mut;
            float num = (2.0f * mup * mut + c1) * (2.0f * spt + c2);
            float den = (mup * mup + mut * mut + c1) * (spp + stt + c2);
            float ssim = __fdividef(num, den + 1e-6f);
            lsum += fmaxf((1.0f - ssim) * 0.5f, 0.0f);
        }
        acc(orow - 5, Sub{});  // drop top row of window
    }

    #pragma unroll
    for (int off = 32; off; off >>= 1) lsum += __shfl_down(lsum, off);
    if (c == 0) red[wid] = lsum;
    __syncthreads();
    if (threadIdx.x == 0) {
        float s = 0.0f;
        #pragma unroll
        for (int w = 0; w < 8; ++w) s += red[w];
        parts[bx] = s;
    }
}

// ---------------- kernel 4: deterministic final reduce ----------------
__global__ void finish(const float* __restrict__ parts, float* __restrict__ out,
                       int n, float invN) {
    float s = 0.0f;
    for (int i = threadIdx.x; i < n; i += 256) s += parts[i];
    #pragma unroll
    for (int off = 32; off; off >>= 1) s += __shfl_down(s, off);
    __shared__ float sw[4];
    int wid = threadIdx.x >> 6, lane = threadIdx.x & 63;
    if (lane == 0) sw[wid] = s;
    __syncthreads();
    if (threadIdx.x == 0) out[0] = ((sw[0] + sw[1]) + (sw[2] + sw[3])) * invN;
}

extern "C" void kernel_launch(void* const* d_in, const int* in_sizes, int n_in,
                              void* d_out, int out_size, void* d_ws, size_t ws_size,
                              hipStream_t stream) {
    const float* pred = (const float*)d_in[0];
    const float* targ = (const float*)d_in[1];
    float* out = (float*)d_out;
    int planes = in_sizes[0] / PLANE;  // 96
    int G = planes * 8;                // 768 blocks

    float* ws   = (float*)d_ws;
    float* pmx  = ws;                  // G
    float* pmn  = ws + G;              // G
    float* c1s  = ws + 2 * G;          // planes
    float* c2s  = ws + 2 * G + planes; // planes
    float* prts = ws + 2 * G + 2 * planes;  // G

    minmax_part<<<G, 256, 0, stream>>>(pred, targ, pmx, pmn);
    minmax_fin<<<(planes + 127) / 128, 128, 0, stream>>>(pmx, pmn, c1s, c2s, planes);
    ssim_main<<<G, 512, 0, stream>>>(pred, targ, c1s, c2s, prts);
    float invN = 1.0f / ((float)planes * (float)PLANE);
    finish<<<1, 256, 0, stream>>>(prts, out, G, invN);
}

// Round 5
// 140.586 us; speedup vs baseline: 6.1946x; 6.1946x over previous
//
#include <hip/hip_runtime.h>

constexpr int Wd = 512;
constexpr int PLANE = 512 * 512;

struct Add { static constexpr bool value = true; };
struct Sub { static constexpr bool value = false; };

// ---------------- kernel 1: per-plane-segment min/max partials ----------------
__global__ __launch_bounds__(256) void minmax_part(const float* __restrict__ pred,
                                                   const float* __restrict__ targ,
                                                   float* __restrict__ pmx,
                                                   float* __restrict__ pmn) {
    int bx = blockIdx.x;
    int plane = bx >> 3, seg = bx & 7;
    size_t base = (size_t)plane * PLANE + (size_t)seg * 32768;
    const float4* p4 = reinterpret_cast<const float4*>(pred + base);
    const float4* t4 = reinterpret_cast<const float4*>(targ + base);
    float mx = -3.0e38f, mn = 3.0e38f;
    for (int i = threadIdx.x; i < 8192; i += 256) {
        float4 a = p4[i], b = t4[i];
        mx = fmaxf(mx, fmaxf(fmaxf(fmaxf(a.x, b.x), fmaxf(a.y, b.y)),
                             fmaxf(fmaxf(a.z, b.z), fmaxf(a.w, b.w))));
        mn = fminf(mn, fminf(fminf(fminf(a.x, b.x), fminf(a.y, b.y)),
                             fminf(fminf(a.z, b.z), fminf(a.w, b.w))));
    }
    #pragma unroll
    for (int off = 32; off; off >>= 1) {
        mx = fmaxf(mx, __shfl_down(mx, off));
        mn = fminf(mn, __shfl_down(mn, off));
    }
    __shared__ float smx[4], smn[4];
    int wid = threadIdx.x >> 6, lane = threadIdx.x & 63;
    if (lane == 0) { smx[wid] = mx; smn[wid] = mn; }
    __syncthreads();
    if (threadIdx.x == 0) {
        pmx[bx] = fmaxf(fmaxf(smx[0], smx[1]), fmaxf(smx[2], smx[3]));
        pmn[bx] = fminf(fminf(smn[0], smn[1]), fminf(smn[2], smn[3]));
    }
}

// ---------------- kernel 2: finalize c1/c2 per plane ----------------
__global__ void minmax_fin(const float* __restrict__ pmx, const float* __restrict__ pmn,
                           float* __restrict__ c1s, float* __restrict__ c2s, int planes) {
    int p = blockIdx.x * blockDim.x + threadIdx.x;
    if (p < planes) {
        float mx = -3.0e38f, mn = 3.0e38f;
        for (int s = 0; s < 8; ++s) {
            mx = fmaxf(mx, pmx[p * 8 + s]);
            mn = fminf(mn, pmn[p * 8 + s]);
        }
        float dr = fmaxf(mx - mn, 1e-6f);
        float a = 0.01f * dr, b = 0.03f * dr;
        c1s[p] = a * a;
        c2s[p] = b * b;
    }
}

// ---------------- kernel 3: fused separable SSIM, shuffle-based ----------------
// Grid: planes*8 blocks x 512 threads = 8 independent waves/block. Each wave
// owns 8 output rows; lane c owns columns 8c..8c+7. Vertical 11-row running
// box sums of {p,t,pp,tt,pt} in registers; horizontal 11-col box sum via
// per-lane prefix sums + neighbor-lane __shfl. No LDS tiles, no barriers.
// NOTE: no min-waves bound — forcing 6 waves/EU (R3) capped VGPRs at ~85 and
// spilled ~1.9 GB of scratch (837 us). Let the allocator use its natural ~100.
__global__ __launch_bounds__(512) void ssim_main(const float* __restrict__ pred,
                                                 const float* __restrict__ targ,
                                                 const float* __restrict__ c1s,
                                                 const float* __restrict__ c2s,
                                                 float* __restrict__ parts) {
    __shared__ float red[8];
    int bx = blockIdx.x;
    int plane = bx >> 3, tile = bx & 7;
    int wid = threadIdx.x >> 6, c = threadIdx.x & 63;
    const float c1 = c1s[plane], c2 = c2s[plane];
    const float* Pg = pred + (size_t)plane * PLANE;
    const float* Tg = targ + (size_t)plane * PLANE;
    int r0 = tile * 64 + wid * 8;  // first output row of this wave
    const bool lane0 = (c == 0), lane63 = (c == 63);

    float vsP[8], vsT[8], vsPP[8], vsTT[8], vsPT[8];
    #pragma unroll
    for (int k = 0; k < 8; ++k) { vsP[k] = 0; vsT[k] = 0; vsPP[k] = 0; vsTT[k] = 0; vsPT[k] = 0; }

    // S = Add (row enters window) or Sub (row leaves window)
    auto acc = [&](int r, auto S) {
        if ((unsigned)r < 512u) {
            const float4* prow = reinterpret_cast<const float4*>(Pg + (size_t)r * Wd);
            const float4* trow = reinterpret_cast<const float4*>(Tg + (size_t)r * Wd);
            float4 a0 = prow[2 * c], a1 = prow[2 * c + 1];
            float4 b0 = trow[2 * c], b1 = trow[2 * c + 1];
            float pa[8] = {a0.x, a0.y, a0.z, a0.w, a1.x, a1.y, a1.z, a1.w};
            float tb[8] = {b0.x, b0.y, b0.z, b0.w, b1.x, b1.y, b1.z, b1.w};
            #pragma unroll
            for (int k = 0; k < 8; ++k) {
                if (decltype(S)::value) {
                    vsP[k]  += pa[k];
                    vsT[k]  += tb[k];
                    vsPP[k] = fmaf(pa[k], pa[k], vsPP[k]);
                    vsTT[k] = fmaf(tb[k], tb[k], vsTT[k]);
                    vsPT[k] = fmaf(pa[k], tb[k], vsPT[k]);
                } else {
                    vsP[k]  -= pa[k];
                    vsT[k]  -= tb[k];
                    vsPP[k] = fmaf(-pa[k], pa[k], vsPP[k]);
                    vsTT[k] = fmaf(-tb[k], tb[k], vsTT[k]);
                    vsPT[k] = fmaf(-pa[k], tb[k], vsPT[k]);
                }
            }
        }
    };

    // Horizontal 11-tap box sum over this lane's 8 columns using neighbor shfl.
    auto hsum = [&](const float v[8], float H[8]) {
        float P[8];
        P[0] = v[0];
        #pragma unroll
        for (int k = 1; k < 8; ++k) P[k] = P[k - 1] + v[k];
        float T = P[7];
        float Tm  = __shfl_up(T, 1);
        float Pm2 = __shfl_up(P[2], 1);
        float Pm3 = __shfl_up(P[3], 1);
        float Pm4 = __shfl_up(P[4], 1);
        float Pm5 = __shfl_up(P[5], 1);
        float Pm6 = __shfl_up(P[6], 1);
        if (lane0) { Tm = 0; Pm2 = 0; Pm3 = 0; Pm4 = 0; Pm5 = 0; Pm6 = 0; }
        float Pp0 = __shfl_down(P[0], 1);
        float Pp1 = __shfl_down(P[1], 1);
        float Pp2 = __shfl_down(P[2], 1);
        float Pp3 = __shfl_down(P[3], 1);
        float Pp4 = __shfl_down(P[4], 1);
        if (lane63) { Pp0 = 0; Pp1 = 0; Pp2 = 0; Pp3 = 0; Pp4 = 0; }
        H[0] = (Tm - Pm2) + P[5];
        H[1] = (Tm - Pm3) + P[6];
        H[2] = (Tm - Pm4) + T;
        H[3] = (Tm - Pm5) + (T + Pp0);
        H[4] = (Tm - Pm6) + (T + Pp1);
        H[5] = T + Pp2;
        H[6] = (T - P[0]) + Pp3;
        H[7] = (T - P[1]) + Pp4;
    };

    // init vertical window: rows r0-5 .. r0+4
    for (int r = r0 - 5; r <= r0 + 4; ++r) acc(r, Add{});

    float lsum = 0.0f;
    #pragma unroll 1
    for (int it = 0; it < 8; ++it) {
        int orow = r0 + it;
        acc(orow + 5, Add{});  // window now rows orow-5..orow+5

        float H[5][8];
        hsum(vsP,  H[0]);
        hsum(vsT,  H[1]);
        hsum(vsPP, H[2]);
        hsum(vsTT, H[3]);
        hsum(vsPT, H[4]);

        constexpr float inv = 1.0f / 121.0f;
        #pragma unroll
        for (int i = 0; i < 8; ++i) {
            float mup = H[0][i] * inv, mut = H[1][i] * inv;
            float spp = fmaxf(H[2][i] * inv - mup * mup, 0.0f);
            float stt = fmaxf(H[3][i] * inv - mut * mut, 0.0f);
            float spt = H[4][i] * inv - mup * mut;
            float num = (2.0f * mup * mut + c1) * (2.0f * spt + c2);
            float den = (mup * mup + mut * mut + c1) * (spp + stt + c2);
            float ssim = __fdividef(num, den + 1e-6f);
            lsum += fmaxf((1.0f - ssim) * 0.5f, 0.0f);
        }
        acc(orow - 5, Sub{});  // drop top row of window
    }

    #pragma unroll
    for (int off = 32; off; off >>= 1) lsum += __shfl_down(lsum, off);
    if (c == 0) red[wid] = lsum;
    __syncthreads();
    if (threadIdx.x == 0) {
        float s = 0.0f;
        #pragma unroll
        for (int w = 0; w < 8; ++w) s += red[w];
        parts[bx] = s;
    }
}

// ---------------- kernel 4: deterministic final reduce ----------------
__global__ void finish(const float* __restrict__ parts, float* __restrict__ out,
                       int n, float invN) {
    float s = 0.0f;
    for (int i = threadIdx.x; i < n; i += 256) s += parts[i];
    #pragma unroll
    for (int off = 32; off; off >>= 1) s += __shfl_down(s, off);
    __shared__ float sw[4];
    int wid = threadIdx.x >> 6, lane = threadIdx.x & 63;
    if (lane == 0) sw[wid] = s;
    __syncthreads();
    if (threadIdx.x == 0) out[0] = ((sw[0] + sw[1]) + (sw[2] + sw[3])) * invN;
}

extern "C" void kernel_launch(void* const* d_in, const int* in_sizes, int n_in,
                              void* d_out, int out_size, void* d_ws, size_t ws_size,
                              hipStream_t stream) {
    const float* pred = (const float*)d_in[0];
    const float* targ = (const float*)d_in[1];
    float* out = (float*)d_out;
    int planes = in_sizes[0] / PLANE;  // 96
    int G = planes * 8;                // 768 blocks

    float* ws   = (float*)d_ws;
    float* pmx  = ws;                  // G
    float* pmn  = ws + G;              // G
    float* c1s  = ws + 2 * G;          // planes
    float* c2s  = ws + 2 * G + planes; // planes
    float* prts = ws + 2 * G + 2 * planes;  // G

    minmax_part<<<G, 256, 0, stream>>>(pred, targ, pmx, pmn);
    minmax_fin<<<(planes + 127) / 128, 128, 0, stream>>>(pmx, pmn, c1s, c2s, planes);
    ssim_main<<<G, 512, 0, stream>>>(pred, targ, c1s, c2s, prts);
    float invN = 1.0f / ((float)planes * (float)PLANE);
    finish<<<1, 256, 0, stream>>>(prts, out, G, invN);
}

// Round 6
// 125.125 us; speedup vs baseline: 6.9600x; 1.1236x over previous
//
#include <hip/hip_runtime.h>

constexpr int Wd = 512;
constexpr int PLANE = 512 * 512;

// ---------------- kernel 1: per-plane-segment min/max partials ----------------
__global__ __launch_bounds__(256) void minmax_part(const float* __restrict__ pred,
                                                   const float* __restrict__ targ,
                                                   float* __restrict__ pmx,
                                                   float* __restrict__ pmn) {
    int bx = blockIdx.x;
    int plane = bx >> 3, seg = bx & 7;
    size_t base = (size_t)plane * PLANE + (size_t)seg * 32768;
    const float4* p4 = reinterpret_cast<const float4*>(pred + base);
    const float4* t4 = reinterpret_cast<const float4*>(targ + base);
    float mx = -3.0e38f, mn = 3.0e38f;
    for (int i = threadIdx.x; i < 8192; i += 256) {
        float4 a = p4[i], b = t4[i];
        mx = fmaxf(mx, fmaxf(fmaxf(fmaxf(a.x, b.x), fmaxf(a.y, b.y)),
                             fmaxf(fmaxf(a.z, b.z), fmaxf(a.w, b.w))));
        mn = fminf(mn, fminf(fminf(fminf(a.x, b.x), fminf(a.y, b.y)),
                             fminf(fminf(a.z, b.z), fminf(a.w, b.w))));
    }
    #pragma unroll
    for (int off = 32; off; off >>= 1) {
        mx = fmaxf(mx, __shfl_down(mx, off));
        mn = fminf(mn, __shfl_down(mn, off));
    }
    __shared__ float smx[4], smn[4];
    int wid = threadIdx.x >> 6, lane = threadIdx.x & 63;
    if (lane == 0) { smx[wid] = mx; smn[wid] = mn; }
    __syncthreads();
    if (threadIdx.x == 0) {
        pmx[bx] = fmaxf(fmaxf(smx[0], smx[1]), fmaxf(smx[2], smx[3]));
        pmn[bx] = fminf(fminf(smn[0], smn[1]), fminf(smn[2], smn[3]));
    }
}

// ---------------- kernel 2: finalize c1/c2 per plane ----------------
__global__ void minmax_fin(const float* __restrict__ pmx, const float* __restrict__ pmn,
                           float* __restrict__ c1s, float* __restrict__ c2s, int planes) {
    int p = blockIdx.x * blockDim.x + threadIdx.x;
    if (p < planes) {
        float mx = -3.0e38f, mn = 3.0e38f;
        for (int s = 0; s < 8; ++s) {
            mx = fmaxf(mx, pmx[p * 8 + s]);
            mn = fminf(mn, pmn[p * 8 + s]);
        }
        float dr = fmaxf(mx - mn, 1e-6f);
        float a = 0.01f * dr, b = 0.03f * dr;
        c1s[p] = a * a;
        c2s[p] = b * b;
    }
}

// ---------------- kernel 3: fused separable SSIM, shuffle + SW pipeline ------
// 768 blocks x 256 thr = 4 waves/block; wave owns 16 output rows, lane owns
// 8 cols. Vertical 11-row running sums in regs; horizontal 11-tap via
// neighbor __shfl. Software pipeline: next iteration's enter/leave row loads
// are issued one full iteration early (2x-unrolled loop renames the pipeline
// registers, no v_mov copies).
__global__ __launch_bounds__(256) void ssim_main(const float* __restrict__ pred,
                                                 const float* __restrict__ targ,
                                                 const float* __restrict__ c1s,
                                                 const float* __restrict__ c2s,
                                                 float* __restrict__ parts) {
    __shared__ float red[4];
    int bx = blockIdx.x;
    int plane = bx >> 3, tile = bx & 7;
    int wid = threadIdx.x >> 6, c = threadIdx.x & 63;
    const float c1 = c1s[plane], c2 = c2s[plane];
    const float* Pg = pred + (size_t)plane * PLANE;
    const float* Tg = targ + (size_t)plane * PLANE;
    int r0 = tile * 64 + wid * 16;  // first output row of this wave
    const bool lane0 = (c == 0), lane63 = (c == 63);

    float vsP[8], vsT[8], vsPP[8], vsTT[8], vsPT[8];
    #pragma unroll
    for (int k = 0; k < 8; ++k) { vsP[k] = 0; vsT[k] = 0; vsPP[k] = 0; vsTT[k] = 0; vsPT[k] = 0; }

    struct RowData { float4 a0, a1, b0, b1; };

    auto load_row = [&](int r) -> RowData {
        RowData d;
        if ((unsigned)r < 512u) {
            const float4* prow = reinterpret_cast<const float4*>(Pg + (size_t)r * Wd);
            const float4* trow = reinterpret_cast<const float4*>(Tg + (size_t)r * Wd);
            d.a0 = prow[2 * c]; d.a1 = prow[2 * c + 1];
            d.b0 = trow[2 * c]; d.b1 = trow[2 * c + 1];
        } else {
            d.a0 = d.a1 = d.b0 = d.b1 = make_float4(0, 0, 0, 0);
        }
        return d;
    };

    // add = true: row enters window; false: row leaves
    auto acc_data = [&](const RowData& d, bool add) {
        float pa[8] = {d.a0.x, d.a0.y, d.a0.z, d.a0.w, d.a1.x, d.a1.y, d.a1.z, d.a1.w};
        float tb[8] = {d.b0.x, d.b0.y, d.b0.z, d.b0.w, d.b1.x, d.b1.y, d.b1.z, d.b1.w};
        #pragma unroll
        for (int k = 0; k < 8; ++k) {
            if (add) {
                vsP[k]  += pa[k];
                vsT[k]  += tb[k];
                vsPP[k] = fmaf(pa[k], pa[k], vsPP[k]);
                vsTT[k] = fmaf(tb[k], tb[k], vsTT[k]);
                vsPT[k] = fmaf(pa[k], tb[k], vsPT[k]);
            } else {
                vsP[k]  -= pa[k];
                vsT[k]  -= tb[k];
                vsPP[k] = fmaf(-pa[k], pa[k], vsPP[k]);
                vsTT[k] = fmaf(-tb[k], tb[k], vsTT[k]);
                vsPT[k] = fmaf(-pa[k], tb[k], vsPT[k]);
            }
        }
    };

    auto hsum = [&](const float v[8], float H[8]) {
        float P[8];
        P[0] = v[0];
        #pragma unroll
        for (int k = 1; k < 8; ++k) P[k] = P[k - 1] + v[k];
        float T = P[7];
        float Tm  = __shfl_up(T, 1);
        float Pm2 = __shfl_up(P[2], 1);
        float Pm3 = __shfl_up(P[3], 1);
        float Pm4 = __shfl_up(P[4], 1);
        float Pm5 = __shfl_up(P[5], 1);
        float Pm6 = __shfl_up(P[6], 1);
        if (lane0) { Tm = 0; Pm2 = 0; Pm3 = 0; Pm4 = 0; Pm5 = 0; Pm6 = 0; }
        float Pp0 = __shfl_down(P[0], 1);
        float Pp1 = __shfl_down(P[1], 1);
        float Pp2 = __shfl_down(P[2], 1);
        float Pp3 = __shfl_down(P[3], 1);
        float Pp4 = __shfl_down(P[4], 1);
        if (lane63) { Pp0 = 0; Pp1 = 0; Pp2 = 0; Pp3 = 0; Pp4 = 0; }
        H[0] = (Tm - Pm2) + P[5];
        H[1] = (Tm - Pm3) + P[6];
        H[2] = (Tm - Pm4) + T;
        H[3] = (Tm - Pm5) + (T + Pp0);
        H[4] = (Tm - Pm6) + (T + Pp1);
        H[5] = T + Pp2;
        H[6] = (T - P[0]) + Pp3;
        H[7] = (T - P[1]) + Pp4;
    };

    float lsum = 0.0f;

    auto body = [&](int it, const RowData& E, const RowData& Lv, RowData& En, RowData& Ln) {
        // issue next iteration's loads first (consumed next body -> ~1 iter of cover)
        En = load_row(r0 + it + 6);
        Ln = load_row(r0 + it - 4);

        acc_data(E, true);   // window now rows (r0+it)-5 .. (r0+it)+5

        float H[5][8];
        hsum(vsP,  H[0]);
        hsum(vsT,  H[1]);
        hsum(vsPP, H[2]);
        hsum(vsTT, H[3]);
        hsum(vsPT, H[4]);

        constexpr float inv = 1.0f / 121.0f;
        #pragma unroll
        for (int i = 0; i < 8; ++i) {
            float mup = H[0][i] * inv, mut = H[1][i] * inv;
            float spp = fmaxf(H[2][i] * inv - mup * mup, 0.0f);
            float stt = fmaxf(H[3][i] * inv - mut * mut, 0.0f);
            float spt = H[4][i] * inv - mup * mut;
            float num = (2.0f * mup * mut + c1) * (2.0f * spt + c2);
            float den = (mup * mup + mut * mut + c1) * (spp + stt + c2);
            float ssim = __fdividef(num, den + 1e-6f);
            lsum += fmaxf((1.0f - ssim) * 0.5f, 0.0f);
        }
        acc_data(Lv, false);  // drop row (r0+it)-5
    };

    // init vertical window: rows r0-5 .. r0+4
    for (int r = r0 - 5; r <= r0 + 4; ++r) acc_data(load_row(r), true);

    // pipeline prologue
    RowData E0 = load_row(r0 + 5);   // enter row for it=0
    RowData L0 = load_row(r0 - 5);   // leave row for it=0
    RowData E1, L1;

    #pragma unroll 1
    for (int it = 0; it < 16; it += 2) {
        body(it,     E0, L0, E1, L1);
        body(it + 1, E1, L1, E0, L0);
    }

    #pragma unroll
    for (int off = 32; off; off >>= 1) lsum += __shfl_down(lsum, off);
    if (c == 0) red[wid] = lsum;
    __syncthreads();
    if (threadIdx.x == 0) parts[bx] = (red[0] + red[1]) + (red[2] + red[3]);
}

// ---------------- kernel 4: deterministic final reduce ----------------
__global__ void finish(const float* __restrict__ parts, float* __restrict__ out,
                       int n, float invN) {
    float s = 0.0f;
    for (int i = threadIdx.x; i < n; i += 256) s += parts[i];
    #pragma unroll
    for (int off = 32; off; off >>= 1) s += __shfl_down(s, off);
    __shared__ float sw[4];
    int wid = threadIdx.x >> 6, lane = threadIdx.x & 63;
    if (lane == 0) sw[wid] = s;
    __syncthreads();
    if (threadIdx.x == 0) out[0] = ((sw[0] + sw[1]) + (sw[2] + sw[3])) * invN;
}

extern "C" void kernel_launch(void* const* d_in, const int* in_sizes, int n_in,
                              void* d_out, int out_size, void* d_ws, size_t ws_size,
                              hipStream_t stream) {
    const float* pred = (const float*)d_in[0];
    const float* targ = (const float*)d_in[1];
    float* out = (float*)d_out;
    int planes = in_sizes[0] / PLANE;  // 96
    int G = planes * 8;                // 768 blocks

    float* ws   = (float*)d_ws;
    float* pmx  = ws;                  // G
    float* pmn  = ws + G;              // G
    float* c1s  = ws + 2 * G;          // planes
    float* c2s  = ws + 2 * G + planes; // planes
    float* prts = ws + 2 * G + 2 * planes;  // G

    minmax_part<<<G, 256, 0, stream>>>(pred, targ, pmx, pmn);
    minmax_fin<<<(planes + 127) / 128, 128, 0, stream>>>(pmx, pmn, c1s, c2s, planes);
    ssim_main<<<G, 256, 0, stream>>>(pred, targ, c1s, c2s, prts);
    float invN = 1.0f / ((float)planes * (float)PLANE);
    finish<<<1, 256, 0, stream>>>(prts, out, G, invN);
}

// Round 7
// 121.421 us; speedup vs baseline: 7.1723x; 1.0305x over previous
//
#include <hip/hip_runtime.h>

constexpr int Wd = 512;
constexpr int PLANE = 512 * 512;

// ---------------- kernel 1: per-plane-segment min/max partials ----------------
__global__ __launch_bounds__(256) void minmax_part(const float* __restrict__ pred,
                                                   const float* __restrict__ targ,
                                                   float* __restrict__ pmx,
                                                   float* __restrict__ pmn) {
    int bx = blockIdx.x;
    int plane = bx >> 3, seg = bx & 7;
    size_t base = (size_t)plane * PLANE + (size_t)seg * 32768;
    const float4* p4 = reinterpret_cast<const float4*>(pred + base);
    const float4* t4 = reinterpret_cast<const float4*>(targ + base);
    float mx = -3.0e38f, mn = 3.0e38f;
    for (int i = threadIdx.x; i < 8192; i += 256) {
        float4 a = p4[i], b = t4[i];
        mx = fmaxf(mx, fmaxf(fmaxf(fmaxf(a.x, b.x), fmaxf(a.y, b.y)),
                             fmaxf(fmaxf(a.z, b.z), fmaxf(a.w, b.w))));
        mn = fminf(mn, fminf(fminf(fminf(a.x, b.x), fminf(a.y, b.y)),
                             fminf(fminf(a.z, b.z), fminf(a.w, b.w))));
    }
    #pragma unroll
    for (int off = 32; off; off >>= 1) {
        mx = fmaxf(mx, __shfl_down(mx, off));
        mn = fminf(mn, __shfl_down(mn, off));
    }
    __shared__ float smx[4], smn[4];
    int wid = threadIdx.x >> 6, lane = threadIdx.x & 63;
    if (lane == 0) { smx[wid] = mx; smn[wid] = mn; }
    __syncthreads();
    if (threadIdx.x == 0) {
        pmx[bx] = fmaxf(fmaxf(smx[0], smx[1]), fmaxf(smx[2], smx[3]));
        pmn[bx] = fminf(fminf(smn[0], smn[1]), fminf(smn[2], smn[3]));
    }
}

// ---------------- kernel 2: finalize c1/c2 per plane (pre-scaled by 121^2) ----
__global__ void minmax_fin(const float* __restrict__ pmx, const float* __restrict__ pmn,
                           float* __restrict__ c1s, float* __restrict__ c2s, int planes) {
    int p = blockIdx.x * blockDim.x + threadIdx.x;
    if (p < planes) {
        float mx = -3.0e38f, mn = 3.0e38f;
        for (int s = 0; s < 8; ++s) {
            mx = fmaxf(mx, pmx[p * 8 + s]);
            mn = fminf(mn, pmn[p * 8 + s]);
        }
        float dr = fmaxf(mx - mn, 1e-6f);
        // c1' = (0.01 dr)^2 * 121^2 ; c2' = (0.03 dr)^2 * 121^2
        c1s[p] = 1.4641f * dr * dr;
        c2s[p] = 13.1769f * dr * dr;
    }
}

// ---------------- kernel 3: fused separable SSIM ------------------------------
// 768 blocks x 128 thr = 2 waves/block; wave owns 32 output rows, lane owns
// 8 cols. Vertical 11-row running sums in regs (init loads batched 5+5 to
// keep 20 loads in flight instead of a serial 10-row chain); horizontal
// 11-tap via neighbor __shfl; enter/leave row loads prefetched one iteration
// ahead. 1/121 normalization folded into c1/c2/EPS (done in minmax_fin).
__global__ __launch_bounds__(128) void ssim_main(const float* __restrict__ pred,
                                                 const float* __restrict__ targ,
                                                 const float* __restrict__ c1s,
                                                 const float* __restrict__ c2s,
                                                 float* __restrict__ parts) {
    __shared__ float red[2];
    int bx = blockIdx.x;
    int plane = bx >> 3, tile = bx & 7;
    int wid = threadIdx.x >> 6, c = threadIdx.x & 63;
    const float c1 = c1s[plane], c2 = c2s[plane];
    const float* Pg = pred + (size_t)plane * PLANE;
    const float* Tg = targ + (size_t)plane * PLANE;
    int r0 = tile * 64 + wid * 32;  // first output row of this wave
    const bool lane0 = (c == 0), lane63 = (c == 63);

    float vsP[8], vsT[8], vsPP[8], vsTT[8], vsPT[8];
    #pragma unroll
    for (int k = 0; k < 8; ++k) { vsP[k] = 0; vsT[k] = 0; vsPP[k] = 0; vsTT[k] = 0; vsPT[k] = 0; }

    struct RowData { float4 a0, a1, b0, b1; };

    auto load_row = [&](int r) -> RowData {
        RowData d;
        if ((unsigned)r < 512u) {
            const float4* prow = reinterpret_cast<const float4*>(Pg + (size_t)r * Wd);
            const float4* trow = reinterpret_cast<const float4*>(Tg + (size_t)r * Wd);
            d.a0 = prow[2 * c]; d.a1 = prow[2 * c + 1];
            d.b0 = trow[2 * c]; d.b1 = trow[2 * c + 1];
        } else {
            d.a0 = d.a1 = d.b0 = d.b1 = make_float4(0, 0, 0, 0);
        }
        return d;
    };

    auto acc_data = [&](const RowData& d, bool add) {
        float pa[8] = {d.a0.x, d.a0.y, d.a0.z, d.a0.w, d.a1.x, d.a1.y, d.a1.z, d.a1.w};
        float tb[8] = {d.b0.x, d.b0.y, d.b0.z, d.b0.w, d.b1.x, d.b1.y, d.b1.z, d.b1.w};
        #pragma unroll
        for (int k = 0; k < 8; ++k) {
            if (add) {
                vsP[k]  += pa[k];
                vsT[k]  += tb[k];
                vsPP[k] = fmaf(pa[k], pa[k], vsPP[k]);
                vsTT[k] = fmaf(tb[k], tb[k], vsTT[k]);
                vsPT[k] = fmaf(pa[k], tb[k], vsPT[k]);
            } else {
                vsP[k]  -= pa[k];
                vsT[k]  -= tb[k];
                vsPP[k] = fmaf(-pa[k], pa[k], vsPP[k]);
                vsTT[k] = fmaf(-tb[k], tb[k], vsTT[k]);
                vsPT[k] = fmaf(-pa[k], tb[k], vsPT[k]);
            }
        }
    };

    auto hsum = [&](const float v[8], float H[8]) {
        float P[8];
        P[0] = v[0];
        #pragma unroll
        for (int k = 1; k < 8; ++k) P[k] = P[k - 1] + v[k];
        float T = P[7];
        float Tm  = __shfl_up(T, 1);
        float Pm2 = __shfl_up(P[2], 1);
        float Pm3 = __shfl_up(P[3], 1);
        float Pm4 = __shfl_up(P[4], 1);
        float Pm5 = __shfl_up(P[5], 1);
        float Pm6 = __shfl_up(P[6], 1);
        if (lane0) { Tm = 0; Pm2 = 0; Pm3 = 0; Pm4 = 0; Pm5 = 0; Pm6 = 0; }
        float Pp0 = __shfl_down(P[0], 1);
        float Pp1 = __shfl_down(P[1], 1);
        float Pp2 = __shfl_down(P[2], 1);
        float Pp3 = __shfl_down(P[3], 1);
        float Pp4 = __shfl_down(P[4], 1);
        if (lane63) { Pp0 = 0; Pp1 = 0; Pp2 = 0; Pp3 = 0; Pp4 = 0; }
        H[0] = (Tm - Pm2) + P[5];
        H[1] = (Tm - Pm3) + P[6];
        H[2] = (Tm - Pm4) + T;
        H[3] = (Tm - Pm5) + (T + Pp0);
        H[4] = (Tm - Pm6) + (T + Pp1);
        H[5] = T + Pp2;
        H[6] = (T - P[0]) + Pp3;
        H[7] = (T - P[1]) + Pp4;
    };

    float lsum = 0.0f;

    auto body = [&](int it, const RowData& E, const RowData& Lv, RowData& En, RowData& Ln) {
        // issue next iteration's loads first (~1 iter of latency cover)
        En = load_row(r0 + it + 6);
        Ln = load_row(r0 + it - 4);

        acc_data(E, true);   // window now rows (r0+it)-5 .. (r0+it)+5

        float H[5][8];
        hsum(vsP,  H[0]);
        hsum(vsT,  H[1]);
        hsum(vsPP, H[2]);
        hsum(vsTT, H[3]);
        hsum(vsPT, H[4]);

        // 121-folded SSIM: mu/sigma scaling absorbed into c1,c2,EPS
        #pragma unroll
        for (int i = 0; i < 8; ++i) {
            float A = H[0][i], B = H[1][i];
            float AB = A * B, A2 = A * A, B2 = B * B;
            float t4 = fmaf(121.0f, H[4][i], -AB);
            float num = (2.0f * AB + c1) * fmaf(2.0f, t4, c2);
            float sp = fmaxf(fmaf(121.0f, H[2][i], -A2), 0.0f);
            float st = fmaxf(fmaf(121.0f, H[3][i], -B2), 0.0f);
            float den = (A2 + B2 + c1) * (sp + st + c2);
            float ssim = __fdividef(num, den + 214.358881f);  // EPS * 121^4
            lsum += fmaxf((1.0f - ssim) * 0.5f, 0.0f);
        }
        acc_data(Lv, false);  // drop row (r0+it)-5
    };

    // init vertical window rows r0-5 .. r0+4, in two 5-row bursts
    {
        RowData D0 = load_row(r0 - 5), D1 = load_row(r0 - 4), D2 = load_row(r0 - 3),
                D3 = load_row(r0 - 2), D4 = load_row(r0 - 1);
        acc_data(D0, true); acc_data(D1, true); acc_data(D2, true);
        acc_data(D3, true); acc_data(D4, true);
        RowData D5 = load_row(r0 + 0), D6 = load_row(r0 + 1), D7 = load_row(r0 + 2),
                D8 = load_row(r0 + 3), D9 = load_row(r0 + 4);
        acc_data(D5, true); acc_data(D6, true); acc_data(D7, true);
        acc_data(D8, true); acc_data(D9, true);
    }

    // pipeline prologue
    RowData E0 = load_row(r0 + 5);   // enter row for it=0
    RowData L0 = load_row(r0 - 5);   // leave row for it=0
    RowData E1, L1;

    #pragma unroll 1
    for (int it = 0; it < 32; it += 2) {
        body(it,     E0, L0, E1, L1);
        body(it + 1, E1, L1, E0, L0);
    }

    #pragma unroll
    for (int off = 32; off; off >>= 1) lsum += __shfl_down(lsum, off);
    if (c == 0) red[wid] = lsum;
    __syncthreads();
    if (threadIdx.x == 0) parts[bx] = red[0] + red[1];
}

// ---------------- kernel 4: deterministic final reduce ----------------
__global__ void finish(const float* __restrict__ parts, float* __restrict__ out,
                       int n, float invN) {
    float s = 0.0f;
    for (int i = threadIdx.x; i < n; i += 256) s += parts[i];
    #pragma unroll
    for (int off = 32; off; off >>= 1) s += __shfl_down(s, off);
    __shared__ float sw[4];
    int wid = threadIdx.x >> 6, lane = threadIdx.x & 63;
    if (lane == 0) sw[wid] = s;
    __syncthreads();
    if (threadIdx.x == 0) out[0] = ((sw[0] + sw[1]) + (sw[2] + sw[3])) * invN;
}

extern "C" void kernel_launch(void* const* d_in, const int* in_sizes, int n_in,
                              void* d_out, int out_size, void* d_ws, size_t ws_size,
                              hipStream_t stream) {
    const float* pred = (const float*)d_in[0];
    const float* targ = (const float*)d_in[1];
    float* out = (float*)d_out;
    int planes = in_sizes[0] / PLANE;  // 96
    int G = planes * 8;                // 768 blocks

    float* ws   = (float*)d_ws;
    float* pmx  = ws;                  // G
    float* pmn  = ws + G;              // G
    float* c1s  = ws + 2 * G;          // planes
    float* c2s  = ws + 2 * G + planes; // planes
    float* prts = ws + 2 * G + 2 * planes;  // G

    minmax_part<<<G, 256, 0, stream>>>(pred, targ, pmx, pmn);
    minmax_fin<<<(planes + 127) / 128, 128, 0, stream>>>(pmx, pmn, c1s, c2s, planes);
    ssim_main<<<G, 128, 0, stream>>>(pred, targ, c1s, c2s, prts);
    float invN = 1.0f / ((float)planes * (float)PLANE);
    finish<<<1, 256, 0, stream>>>(prts, out, G, invN);
}

// Round 8
// 117.810 us; speedup vs baseline: 7.3921x; 1.0306x over previous
//
#include <hip/hip_runtime.h>

constexpr int Wd = 512;
constexpr int PLANE = 512 * 512;

typedef float v2f __attribute__((ext_vector_type(2)));

// ---------------- kernel 1: per-plane-segment min/max partials ----------------
__global__ __launch_bounds__(256) void minmax_part(const float* __restrict__ pred,
                                                   const float* __restrict__ targ,
                                                   float* __restrict__ pmx,
                                                   float* __restrict__ pmn) {
    int bx = blockIdx.x;
    int plane = bx >> 3, seg = bx & 7;
    size_t base = (size_t)plane * PLANE + (size_t)seg * 32768;
    const float4* p4 = reinterpret_cast<const float4*>(pred + base);
    const float4* t4 = reinterpret_cast<const float4*>(targ + base);
    float mx = -3.0e38f, mn = 3.0e38f;
    for (int i = threadIdx.x; i < 8192; i += 256) {
        float4 a = p4[i], b = t4[i];
        mx = fmaxf(mx, fmaxf(fmaxf(fmaxf(a.x, b.x), fmaxf(a.y, b.y)),
                             fmaxf(fmaxf(a.z, b.z), fmaxf(a.w, b.w))));
        mn = fminf(mn, fminf(fminf(fminf(a.x, b.x), fminf(a.y, b.y)),
                             fminf(fminf(a.z, b.z), fminf(a.w, b.w))));
    }
    #pragma unroll
    for (int off = 32; off; off >>= 1) {
        mx = fmaxf(mx, __shfl_down(mx, off));
        mn = fminf(mn, __shfl_down(mn, off));
    }
    __shared__ float smx[4], smn[4];
    int wid = threadIdx.x >> 6, lane = threadIdx.x & 63;
    if (lane == 0) { smx[wid] = mx; smn[wid] = mn; }
    __syncthreads();
    if (threadIdx.x == 0) {
        pmx[bx] = fmaxf(fmaxf(smx[0], smx[1]), fmaxf(smx[2], smx[3]));
        pmn[bx] = fminf(fminf(smn[0], smn[1]), fminf(smn[2], smn[3]));
    }
}

// ---------------- kernel 2: finalize c1/c2 per plane (pre-scaled by 121^2) ----
__global__ void minmax_fin(const float* __restrict__ pmx, const float* __restrict__ pmn,
                           float* __restrict__ c1s, float* __restrict__ c2s, int planes) {
    int p = blockIdx.x * blockDim.x + threadIdx.x;
    if (p < planes) {
        float mx = -3.0e38f, mn = 3.0e38f;
        for (int s = 0; s < 8; ++s) {
            mx = fmaxf(mx, pmx[p * 8 + s]);
            mn = fminf(mn, pmn[p * 8 + s]);
        }
        float dr = fmaxf(mx - mn, 1e-6f);
        c1s[p] = 1.4641f * dr * dr;    // (0.01 dr)^2 * 121^2
        c2s[p] = 13.1769f * dr * dr;   // (0.03 dr)^2 * 121^2
    }
}

// ---------------- kernel 3: fused separable SSIM, packed-f32 math -------------
// 768 blocks x 128 thr = 2 waves/block; wave owns 32 output rows, lane owns 8
// cols. Vertical 11-row running sums kept as v2f[4] (v_pk_add/v_pk_fma —
// 2 floats/inst); horizontal 11-tap via per-lane prefix + neighbor __shfl
// (scalar); SSIM epilogue packed as 4x v2f. 1/121 folded into c1/c2/EPS.
__global__ __launch_bounds__(128) void ssim_main(const float* __restrict__ pred,
                                                 const float* __restrict__ targ,
                                                 const float* __restrict__ c1s,
                                                 const float* __restrict__ c2s,
                                                 float* __restrict__ parts) {
    __shared__ float red[2];
    int bx = blockIdx.x;
    int plane = bx >> 3, tile = bx & 7;
    int wid = threadIdx.x >> 6, c = threadIdx.x & 63;
    const float c1 = c1s[plane], c2 = c2s[plane];
    const v2f c1v = {c1, c1}, c2v = {c2, c2};
    const v2f k121 = {121.0f, 121.0f};
    const float* Pg = pred + (size_t)plane * PLANE;
    const float* Tg = targ + (size_t)plane * PLANE;
    int r0 = tile * 64 + wid * 32;
    const bool lane0 = (c == 0), lane63 = (c == 63);

    v2f vsP[4], vsT[4], vsPP[4], vsTT[4], vsPT[4];
    #pragma unroll
    for (int j = 0; j < 4; ++j) {
        vsP[j] = 0; vsT[j] = 0; vsPP[j] = 0; vsTT[j] = 0; vsPT[j] = 0;
    }

    struct RowData { float4 a0, a1, b0, b1; };

    auto load_row = [&](int r) -> RowData {
        RowData d;
        if ((unsigned)r < 512u) {
            const float4* prow = reinterpret_cast<const float4*>(Pg + (size_t)r * Wd);
            const float4* trow = reinterpret_cast<const float4*>(Tg + (size_t)r * Wd);
            d.a0 = prow[2 * c]; d.a1 = prow[2 * c + 1];
            d.b0 = trow[2 * c]; d.b1 = trow[2 * c + 1];
        } else {
            d.a0 = d.a1 = d.b0 = d.b1 = make_float4(0, 0, 0, 0);
        }
        return d;
    };

    auto acc_data = [&](const RowData& d, bool add) {
        v2f pa[4] = {{d.a0.x, d.a0.y}, {d.a0.z, d.a0.w}, {d.a1.x, d.a1.y}, {d.a1.z, d.a1.w}};
        v2f tb[4] = {{d.b0.x, d.b0.y}, {d.b0.z, d.b0.w}, {d.b1.x, d.b1.y}, {d.b1.z, d.b1.w}};
        #pragma unroll
        for (int j = 0; j < 4; ++j) {
            if (add) {
                vsP[j]  += pa[j];                    // v_pk_add_f32
                vsT[j]  += tb[j];
                vsPP[j] += pa[j] * pa[j];            // contracts to v_pk_fma_f32
                vsTT[j] += tb[j] * tb[j];
                vsPT[j] += pa[j] * tb[j];
            } else {
                vsP[j]  -= pa[j];
                vsT[j]  -= tb[j];
                vsPP[j] -= pa[j] * pa[j];
                vsTT[j] -= tb[j] * tb[j];
                vsPT[j] -= pa[j] * tb[j];
            }
        }
    };

    // Horizontal 11-tap box sum; scalar prefix + neighbor shfl; outputs 4x v2f.
    auto hsum = [&](const v2f v[4], v2f H[4]) {
        float P0 = v[0].x;
        float P1 = P0 + v[0].y;
        float P2 = P1 + v[1].x;
        float P3 = P2 + v[1].y;
        float P4 = P3 + v[2].x;
        float P5 = P4 + v[2].y;
        float P6 = P5 + v[3].x;
        float T  = P6 + v[3].y;
        float Tm  = __shfl_up(T, 1);
        float Pm2 = __shfl_up(P2, 1);
        float Pm3 = __shfl_up(P3, 1);
        float Pm4 = __shfl_up(P4, 1);
        float Pm5 = __shfl_up(P5, 1);
        float Pm6 = __shfl_up(P6, 1);
        if (lane0) { Tm = 0; Pm2 = 0; Pm3 = 0; Pm4 = 0; Pm5 = 0; Pm6 = 0; }
        float Pp0 = __shfl_down(P0, 1);
        float Pp1 = __shfl_down(P1, 1);
        float Pp2 = __shfl_down(P2, 1);
        float Pp3 = __shfl_down(P3, 1);
        float Pp4 = __shfl_down(P4, 1);
        if (lane63) { Pp0 = 0; Pp1 = 0; Pp2 = 0; Pp3 = 0; Pp4 = 0; }
        H[0].x = (Tm - Pm2) + P5;
        H[0].y = (Tm - Pm3) + P6;
        H[1].x = (Tm - Pm4) + T;
        H[1].y = (Tm - Pm5) + (T + Pp0);
        H[2].x = (Tm - Pm6) + (T + Pp1);
        H[2].y = T + Pp2;
        H[3].x = (T - P0) + Pp3;
        H[3].y = (T - P1) + Pp4;
    };

    v2f lsum2 = {0.0f, 0.0f};

    auto body = [&](int it, const RowData& E, const RowData& Lv, RowData& En, RowData& Ln) {
        En = load_row(r0 + it + 6);
        Ln = load_row(r0 + it - 4);

        acc_data(E, true);   // window rows (r0+it)-5 .. (r0+it)+5

        v2f H[5][4];
        hsum(vsP,  H[0]);
        hsum(vsT,  H[1]);
        hsum(vsPP, H[2]);
        hsum(vsTT, H[3]);
        hsum(vsPT, H[4]);

        // packed SSIM epilogue, 2 px per v2f
        #pragma unroll
        for (int j = 0; j < 4; ++j) {
            v2f A = H[0][j], B = H[1][j];
            v2f AB = A * B, A2 = A * A, B2 = B * B;
            v2f t4 = k121 * H[4][j] - AB;                 // pk_fma
            v2f num = (2.0f * AB + c1v) * (2.0f * t4 + c2v);
            v2f sp = k121 * H[2][j] - A2;
            v2f st = k121 * H[3][j] - B2;
            sp.x = fmaxf(sp.x, 0.0f); sp.y = fmaxf(sp.y, 0.0f);
            st.x = fmaxf(st.x, 0.0f); st.y = fmaxf(st.y, 0.0f);
            v2f den = (A2 + B2 + c1v) * (sp + st + c2v);
            float s0 = __fdividef(num.x, den.x + 214.358881f);  // EPS * 121^4
            float s1 = __fdividef(num.y, den.y + 214.358881f);
            v2f loss = {fmaxf((1.0f - s0) * 0.5f, 0.0f),
                        fmaxf((1.0f - s1) * 0.5f, 0.0f)};
            lsum2 += loss;                                // pk_add
        }
        acc_data(Lv, false);
    };

    // init vertical window rows r0-5 .. r0+4, two 5-row bursts
    {
        RowData D0 = load_row(r0 - 5), D1 = load_row(r0 - 4), D2 = load_row(r0 - 3),
                D3 = load_row(r0 - 2), D4 = load_row(r0 - 1);
        acc_data(D0, true); acc_data(D1, true); acc_data(D2, true);
        acc_data(D3, true); acc_data(D4, true);
        RowData D5 = load_row(r0 + 0), D6 = load_row(r0 + 1), D7 = load_row(r0 + 2),
                D8 = load_row(r0 + 3), D9 = load_row(r0 + 4);
        acc_data(D5, true); acc_data(D6, true); acc_data(D7, true);
        acc_data(D8, true); acc_data(D9, true);
    }

    RowData E0 = load_row(r0 + 5);
    RowData L0 = load_row(r0 - 5);
    RowData E1, L1;

    #pragma unroll 1
    for (int it = 0; it < 32; it += 2) {
        body(it,     E0, L0, E1, L1);
        body(it + 1, E1, L1, E0, L0);
    }

    float lsum = lsum2.x + lsum2.y;
    #pragma unroll
    for (int off = 32; off; off >>= 1) lsum += __shfl_down(lsum, off);
    if (c == 0) red[wid] = lsum;
    __syncthreads();
    if (threadIdx.x == 0) parts[bx] = red[0] + red[1];
}

// ---------------- kernel 4: deterministic final reduce ----------------
__global__ void finish(const float* __restrict__ parts, float* __restrict__ out,
                       int n, float invN) {
    float s = 0.0f;
    for (int i = threadIdx.x; i < n; i += 256) s += parts[i];
    #pragma unroll
    for (int off = 32; off; off >>= 1) s += __shfl_down(s, off);
    __shared__ float sw[4];
    int wid = threadIdx.x >> 6, lane = threadIdx.x & 63;
    if (lane == 0) sw[wid] = s;
    __syncthreads();
    if (threadIdx.x == 0) out[0] = ((sw[0] + sw[1]) + (sw[2] + sw[3])) * invN;
}

extern "C" void kernel_launch(void* const* d_in, const int* in_sizes, int n_in,
                              void* d_out, int out_size, void* d_ws, size_t ws_size,
                              hipStream_t stream) {
    const float* pred = (const float*)d_in[0];
    const float* targ = (const float*)d_in[1];
    float* out = (float*)d_out;
    int planes = in_sizes[0] / PLANE;  // 96
    int G = planes * 8;                // 768 blocks

    float* ws   = (float*)d_ws;
    float* pmx  = ws;                  // G
    float* pmn  = ws + G;              // G
    float* c1s  = ws + 2 * G;          // planes
    float* c2s  = ws + 2 * G + planes; // planes
    float* prts = ws + 2 * G + 2 * planes;  // G

    minmax_part<<<G, 256, 0, stream>>>(pred, targ, pmx, pmn);
    minmax_fin<<<(planes + 127) / 128, 128, 0, stream>>>(pmx, pmn, c1s, c2s, planes);
    ssim_main<<<G, 128, 0, stream>>>(pred, targ, c1s, c2s, prts);
    float invN = 1.0f / ((float)planes * (float)PLANE);
    finish<<<1, 256, 0, stream>>>(prts, out, G, invN);
}